// Round 1
// baseline (265.290 us; speedup 1.0000x reference)
//
#include <hip/hip_runtime.h>

typedef unsigned short u16;
using bf16x8 = __attribute__((ext_vector_type(8))) short;   // 8 bf16 (4 VGPRs)
using f32x4  = __attribute__((ext_vector_type(4))) float;   // 4 fp32

__device__ __forceinline__ u16 f2b(float f) {
    __bf16 h = (__bf16)f;
    return __builtin_bit_cast(unsigned short, h);
}
__device__ __forceinline__ float b2f(u16 u) {
    return (float)__builtin_bit_cast(__bf16, u);
}

__device__ __forceinline__ void gload16(const void* g, void* l) {
    __builtin_amdgcn_global_load_lds(
        (const __attribute__((address_space(1))) unsigned int*)g,
        (__attribute__((address_space(3))) unsigned int*)l, 16, 0, 0);
}

// C = A * B^T  (A: MxK row-major, B: NxK row-major), bf16 in, fp32 MFMA accum.
// MODE 0: C_bf16 = acc + bias[col]
// MODE 2: P_bf16 = exp2(acc * wk[col]); atomicAdd(rowsum[row], sum of bf16-rounded P)
// MODE 3: C_f32 = acc / rowsum[row]
template<int MODE>
__global__ __launch_bounds__(256)
void gemm_bt(const u16* __restrict__ A, const u16* __restrict__ B,
             void* __restrict__ Cv, const float* __restrict__ aux,
             float* __restrict__ rowsum,
             int K, int lda, int ldb, int ldc,
             long strA, long strB, long strC, long strAux, long strRS)
{
    __shared__ __align__(16) u16 sA[128 * 64];
    __shared__ __align__(16) u16 sB[128 * 64];

    const int tid  = threadIdx.x;
    const int lane = tid & 63;
    const int wave = tid >> 6;          // 0..3
    const int wm = wave >> 1, wn = wave & 1;   // 2x2 wave grid, 64x64 each
    const int bn0 = blockIdx.x * 128;
    const int bm0 = blockIdx.y * 128;
    const long z  = blockIdx.z;

    const u16* Ab = A + z * strA;
    const u16* Bb = B + z * strB;
    const float* auxp = aux + z * strAux;

    f32x4 acc[4][4] = {};

    const int l16 = lane & 15;
    const int lk8 = (lane >> 4) * 8;

    for (int k0 = 0; k0 < K; k0 += 64) {
        // stage A,B tiles (128x64 bf16 each) via global_load_lds, width 16.
        // LDS dest is linear (wave-uniform base + lane*16); swizzle applied on the
        // GLOBAL source k-chunk so reads can XOR-deswizzle (rule #21).
#pragma unroll
        for (int i = 0; i < 4; ++i) {
            const int c   = i * 256 + tid;
            const int row = c >> 3;
            const int kc  = (c & 7) ^ (row & 7);
            const int ldsoff = (i * 256 + wave * 64) * 8;   // elements
            gload16(Ab + (long)(bm0 + row) * lda + k0 + kc * 8, &sA[ldsoff]);
            gload16(Bb + (long)(bn0 + row) * ldb + k0 + kc * 8, &sB[ldsoff]);
        }
        __syncthreads();
#pragma unroll
        for (int kk = 0; kk < 64; kk += 32) {
            bf16x8 af[4], bg[4];
#pragma unroll
            for (int m = 0; m < 4; ++m) {
                const int row = wm * 64 + m * 16 + l16;
                int byte_off = row * 128 + (kk + lk8) * 2;
                byte_off ^= (row & 7) << 4;                  // st-swizzle deref
                af[m] = *(const bf16x8*)((const char*)sA + byte_off);
            }
#pragma unroll
            for (int n = 0; n < 4; ++n) {
                const int row = wn * 64 + n * 16 + l16;
                int byte_off = row * 128 + (kk + lk8) * 2;
                byte_off ^= (row & 7) << 4;
                bg[n] = *(const bf16x8*)((const char*)sB + byte_off);
            }
#pragma unroll
            for (int m = 0; m < 4; ++m)
#pragma unroll
                for (int n = 0; n < 4; ++n)
                    acc[m][n] = __builtin_amdgcn_mfma_f32_16x16x32_bf16(
                        af[m], bg[n], acc[m][n], 0, 0, 0);
        }
        __syncthreads();
    }

    // C/D layout (m89/m91 verified): col = lane&15, row = (lane>>4)*4 + reg
    const int rg    = lane >> 4;
    const int orow0 = bm0 + wm * 64;
    const int ocol0 = bn0 + wn * 64;

    if constexpr (MODE == 0) {
        u16* Co = (u16*)Cv + z * strC;
        float bias[4];
#pragma unroll
        for (int n = 0; n < 4; ++n) bias[n] = auxp[ocol0 + n * 16 + l16];
#pragma unroll
        for (int m = 0; m < 4; ++m)
#pragma unroll
            for (int n = 0; n < 4; ++n) {
                const int col = ocol0 + n * 16 + l16;
#pragma unroll
                for (int r = 0; r < 4; ++r) {
                    const int row = orow0 + m * 16 + rg * 4 + r;
                    Co[(long)row * ldc + col] = f2b(acc[m][n][r] + bias[n]);
                }
            }
    } else if constexpr (MODE == 2) {
        u16* Co = (u16*)Cv + z * strC;
        float* rsp = rowsum + z * strRS;
        float wkn[4];
#pragma unroll
        for (int n = 0; n < 4; ++n) wkn[n] = auxp[ocol0 + n * 16 + l16];
#pragma unroll
        for (int m = 0; m < 4; ++m)
#pragma unroll
            for (int r = 0; r < 4; ++r) {
                const int row = orow0 + m * 16 + rg * 4 + r;
                float partial = 0.f;
#pragma unroll
                for (int n = 0; n < 4; ++n) {
                    const int col = ocol0 + n * 16 + l16;
                    const float p = exp2f(acc[m][n][r] * wkn[n]);
                    const u16 pb = f2b(p);
                    Co[(long)row * ldc + col] = pb;
                    partial += b2f(pb);   // denominator from bf16-rounded P
                }
                partial += __shfl_xor(partial, 1);
                partial += __shfl_xor(partial, 2);
                partial += __shfl_xor(partial, 4);
                partial += __shfl_xor(partial, 8);
                if (l16 == 0) atomicAdd(&rsp[row], partial);
            }
    } else {  // MODE 3
        float* Co = (float*)Cv + z * strC;
#pragma unroll
        for (int m = 0; m < 4; ++m)
#pragma unroll
            for (int r = 0; r < 4; ++r) {
                const int row = orow0 + m * 16 + rg * 4 + r;
                const float inv = 1.0f / auxp[row];
#pragma unroll
                for (int n = 0; n < 4; ++n) {
                    const int col = ocol0 + n * 16 + l16;
                    Co[(long)row * ldc + col] = acc[m][n][r] * inv;
                }
            }
    }
}

__global__ void cvt_bf16(const float* __restrict__ in, u16* __restrict__ out, int n4) {
    const int i = blockIdx.x * 256 + threadIdx.x;
    if (i >= n4) return;
    const float4 f = ((const float4*)in)[i];
    ushort4 o;
    o.x = f2b(f.x); o.y = f2b(f.y); o.z = f2b(f.z); o.w = f2b(f.w);
    ((ushort4*)out)[i] = o;
}

__global__ void wk_kernel(const float* __restrict__ eig, float* __restrict__ wk, int n) {
    const int i = blockIdx.x * 256 + threadIdx.x;
    if (i >= n) return;
    const float s = 1.0f / (1.0f + expf(-eig[i]));
    wk[i] = s * (float)(1.4426950408889634 / 22.627416997969522);  // log2(e)/sqrt(512)
}

// V [16384][512] bf16 -> Vt [8][512][2048] bf16
__global__ __launch_bounds__(256)
void transpose_v(const u16* __restrict__ V, u16* __restrict__ Vt) {
    __shared__ u16 t[64][65];
    const int tid = threadIdx.x;
    const int d0  = blockIdx.x * 64;
    const int bs0 = blockIdx.y * 64;
#pragma unroll
    for (int i = 0; i < 16; ++i) {
        const int idx = i * 256 + tid;
        const int r = idx >> 6, c = idx & 63;
        t[r][c] = V[(long)(bs0 + r) * 512 + d0 + c];
    }
    __syncthreads();
    const long b = bs0 >> 11;
    const int s0 = bs0 & 2047;
#pragma unroll
    for (int i = 0; i < 16; ++i) {
        const int idx = i * 256 + tid;
        const int dch = idx >> 6, s = idx & 63;
        Vt[(b * 512 + d0 + dch) * 2048 + s0 + s] = t[s][dch];
    }
}

extern "C" void kernel_launch(void* const* d_in, const int* in_sizes, int n_in,
                              void* d_out, int out_size, void* d_ws, size_t ws_size,
                              hipStream_t stream) {
    const float* x  = (const float*)d_in[0];
    const float* ev = (const float*)d_in[1];
    const float* Wq = (const float*)d_in[2];
    const float* bq = (const float*)d_in[3];
    const float* Wk = (const float*)d_in[4];
    const float* bk = (const float*)d_in[5];
    const float* Wv = (const float*)d_in[6];
    const float* bv = (const float*)d_in[7];
    float* out = (float*)d_out;

    char* ws = (char*)d_ws;
    u16*   xb     = (u16*)(ws);                     // 16 MB  x bf16 [16384][512]
    u16*   qkv    = (u16*)(ws + (16ul << 20));      // 48 MB  Q|K|V bf16
    u16*   Vt     = (u16*)(ws + (64ul << 20));      // 16 MB  V^T bf16 [8][512][2048]
    u16*   Wb     = (u16*)(ws + (80ul << 20));      // 1.5 MB Wq|Wk|Wv bf16
    float* biasb  = (float*)(ws + (82ul << 20));    // 6 KB
    float* wk     = (float*)(ws + (83ul << 20));    // 64 KB
    float* rowsum = (float*)(ws + (84ul << 20));    // 64 KB
    u16*   P      = (u16*)(ws + (85ul << 20));      // 64 MB  P bf16 [8][2048][2048]

    cvt_bf16<<<dim3(8192), dim3(256), 0, stream>>>(x, xb, 2097152);
    cvt_bf16<<<dim3(256),  dim3(256), 0, stream>>>(Wq, Wb,          65536);
    cvt_bf16<<<dim3(256),  dim3(256), 0, stream>>>(Wk, Wb + 262144, 65536);
    cvt_bf16<<<dim3(256),  dim3(256), 0, stream>>>(Wv, Wb + 524288, 65536);
    hipMemcpyAsync(biasb,        bq, 512 * 4, hipMemcpyDeviceToDevice, stream);
    hipMemcpyAsync(biasb + 512,  bk, 512 * 4, hipMemcpyDeviceToDevice, stream);
    hipMemcpyAsync(biasb + 1024, bv, 512 * 4, hipMemcpyDeviceToDevice, stream);
    wk_kernel<<<dim3(64), dim3(256), 0, stream>>>(ev, wk, 16384);
    hipMemsetAsync(rowsum, 0, 16384 * 4, stream);

    // QKV projection: M=16384, N=512, K=512, z in {Q,K,V}
    gemm_bt<0><<<dim3(4, 128, 3), dim3(256), 0, stream>>>(
        xb, Wb, qkv, biasb, nullptr,
        512, 512, 512, 512,
        0L, 262144L, 8388608L, 512L, 0L);

    transpose_v<<<dim3(8, 256), dim3(256), 0, stream>>>(qkv + 2 * 8388608L, Vt);

    // scores + exp: per batch, M=N=2048, K=512
    gemm_bt<2><<<dim3(16, 16, 8), dim3(256), 0, stream>>>(
        qkv, qkv + 8388608L, P, wk, rowsum,
        512, 512, 512, 2048,
        1048576L, 1048576L, 4194304L, 2048L, 2048L);

    // PV: per batch, M=2048, N=512, K=2048
    gemm_bt<3><<<dim3(4, 16, 8), dim3(256), 0, stream>>>(
        P, Vt, out, rowsum, nullptr,
        2048, 2048, 2048, 512,
        4194304L, 1048576L, 1048576L, 2048L, 0L);
}